// Round 1
// baseline (76920.337 us; speedup 1.0000x reference)
//
#include <hip/hip_runtime.h>
#include <cstdint>
#include <cstddef>

// Problem constants (T,B,D,H,L = 512,32,512,1024,2)
#define TSTEPS 512
#define NB     32
#define DIN    512
#define HID    1024
#define STRIDE 32768          // NB*HID floats
#define WS_STATE_OFF 16       // floats; [0]=cnt,[1]=gen
#define KEEPF 0.9f            // 1 - p_zoneout

// ---------------- device helpers ----------------
template<int CTRL>
__device__ __forceinline__ float dpp_mov(float x) {
  return __int_as_float(__builtin_amdgcn_update_dpp(
      0, __float_as_int(x), CTRL, 0xf, 0xf, true));
}

// Full wave64 sum, DPP-only (VALU pipe), result broadcast via readlane.
__device__ __forceinline__ float wave_red_sum(float x) {
  x += dpp_mov<0x111>(x);   // row_shr:1
  x += dpp_mov<0x112>(x);   // row_shr:2
  x += dpp_mov<0x114>(x);   // row_shr:4
  x += dpp_mov<0x118>(x);   // row_shr:8
  x += dpp_mov<0x142>(x);   // row_bcast:15
  x += dpp_mov<0x143>(x);   // row_bcast:31
  return __int_as_float(__builtin_amdgcn_readlane(__float_as_int(x), 63));
}

__device__ __forceinline__ float sigmoidf_(float v) {
  return 1.0f / (1.0f + __expf(-v));
}

// Device-scope grid barrier. All stores made agent-visible (threadfence ->
// L2 writeback) before arrival; acquire side invalidates stale caches.
__device__ __forceinline__ void grid_sync(unsigned* cnt, unsigned* gen) {
  __threadfence();
  __syncthreads();
  if (threadIdx.x == 0) {
    unsigned g = __hip_atomic_load(gen, __ATOMIC_RELAXED, __HIP_MEMORY_SCOPE_AGENT);
    unsigned prev = __hip_atomic_fetch_add(cnt, 1u, __ATOMIC_ACQ_REL, __HIP_MEMORY_SCOPE_AGENT);
    if (prev == 255u) {   // last arriver of 256 blocks
      __hip_atomic_store(cnt, 0u, __ATOMIC_RELAXED, __HIP_MEMORY_SCOPE_AGENT);
      __hip_atomic_store(gen, g + 1u, __ATOMIC_RELEASE, __HIP_MEMORY_SCOPE_AGENT);
    } else {
      while (__hip_atomic_load(gen, __ATOMIC_RELAXED, __HIP_MEMORY_SCOPE_AGENT) == g) {
        __builtin_amdgcn_s_sleep(2);
      }
    }
  }
  __syncthreads();
  __threadfence();
}

// Zero barrier words + h/c state (both parities). out0 is written before read.
__global__ void zo_init(float* ws) {
  size_t i = (size_t)blockIdx.x * blockDim.x + threadIdx.x;
  if (i < (size_t)WS_STATE_OFF + 8u * STRIDE) ws[i] = 0.0f;
}

// Persistent kernel: 256 blocks x 256 threads, 1 block/CU.
// wave (global id 0..1023) owns h = wave_id for BOTH layers (8 gate rows).
// lane holds cols [24l,24l+24) of L0 rows and [32l,32l+32) of L1 rows in VGPRs.
__global__ __launch_bounds__(256, 1)
void zo_lstm(const float* __restrict__ x,
             const float* __restrict__ Wih0, const float* __restrict__ Whh0,
             const float* __restrict__ bih0, const float* __restrict__ bhh0,
             const float* __restrict__ Wih1, const float* __restrict__ Whh1,
             const float* __restrict__ bih1, const float* __restrict__ bhh1,
             const float* __restrict__ u_h,  const float* __restrict__ u_c,
             float* __restrict__ out, float* __restrict__ ws)
{
  extern __shared__ float lds[];        // 16384 floats = 64 KiB
  const int tid  = threadIdx.x;
  const int lane = tid & 63;
  const int wv   = tid >> 6;            // wave in block, 0..3
  const int h    = blockIdx.x * 4 + wv; // 0..1023

  unsigned* cnt = (unsigned*)ws;
  unsigned* gen = ((unsigned*)ws) + 1;
  float* st  = ws + WS_STATE_OFF;
  float* h0s = st;                 // [2][NB][HID]
  float* c0s = st + 2 * STRIDE;
  float* h1s = st + 4 * STRIDE;
  float* c1s = st + 6 * STRIDE;
  float* o0s = st + 8 * STRIDE;    // [2][NB][HID] (pre-zoneout h0 -> L1 input)

  // ---- load persistent weights into registers (once) ----
  float w0[96];    // 4 gates x 24 cols of [Wih0|Whh0]
  float w1[128];   // 4 gates x 32 cols of [Wih1|Whh1]
  float bia0[4], bia1[4];
#pragma unroll
  for (int g = 0; g < 4; ++g) {
    const int j = g * HID + h;
    const float* wi0 = Wih0 + (size_t)j * DIN;
    const float* wh0 = Whh0 + (size_t)j * HID;
#pragma unroll
    for (int c = 0; c < 24; ++c) {
      int col = 24 * lane + c;
      w0[g * 24 + c] = (col < DIN) ? wi0[col] : wh0[col - DIN];
    }
    const float* wi1 = Wih1 + (size_t)j * HID;
    const float* wh1 = Whh1 + (size_t)j * HID;
#pragma unroll
    for (int c = 0; c < 32; ++c) {
      int col = 32 * lane + c;
      w1[g * 32 + c] = (col < HID) ? wi1[col] : wh1[col - HID];
    }
    bia0[g] = bih0[j] + bhh0[j];
    bia1[g] = bih1[j] + bhh1[j];
  }

  for (int t = 0; t < TSTEPS; ++t) {
    const int rp = t & 1, wp = rp ^ 1;
    const float* h0r = h0s + rp * STRIDE;  float* h0w = h0s + wp * STRIDE;
    const float* c0r = c0s + rp * STRIDE;  float* c0w = c0s + wp * STRIDE;
    const float* h1r = h1s + rp * STRIDE;  float* h1w = h1s + wp * STRIDE;
    const float* c1r = c1s + rp * STRIDE;  float* c1w = c1s + wp * STRIDE;
    float* o0w = o0s + wp * STRIDE;
    const float* xt = x + (size_t)t * NB * DIN;

    float rg0 = 0.f, rg1 = 0.f, rg2 = 0.f, rg3 = 0.f;

    // ================= Layer 0 =================
    {
      // prologue: stage chunk 0 (4 batches, one per wave)
      {
        const int b = wv;
        const float* xrow = xt + b * DIN;
        const float* hrow = h0r + b * HID;
#pragma unroll
        for (int i = 0; i < 6; ++i) {
          int n = i * 64 + lane;                       // float4 index 0..383
          const float* src = (n < 128) ? (xrow + 4 * n) : (hrow + 4 * n - DIN);
          float4 v = *(const float4*)src;
          int l = n / 6, c4 = n % 6;                   // slot (l,c4) holds col4 = 6l+c4
          *(float4*)(lds + wv * 1536 + c4 * 256 + l * 4) = v;
        }
      }
      __syncthreads();

      for (int cch = 0; cch < 8; ++cch) {
        float4 pf[6];
        if (cch < 7) {   // prefetch next chunk's batch row (global -> regs)
          const int b = (cch + 1) * 4 + wv;
          const float* xrow = xt + b * DIN;
          const float* hrow = h0r + b * HID;
#pragma unroll
          for (int i = 0; i < 6; ++i) {
            int n = i * 64 + lane;
            const float* src = (n < 128) ? (xrow + 4 * n) : (hrow + 4 * n - DIN);
            pf[i] = *(const float4*)src;
          }
        }
        // compute current chunk from LDS buffer (cch&1)
        const float* Bf = lds + (cch & 1) * 6144;
        float acc[4][4];
#pragma unroll
        for (int g = 0; g < 4; ++g)
#pragma unroll
          for (int bb = 0; bb < 4; ++bb) acc[g][bb] = 0.f;

#pragma unroll
        for (int bb = 0; bb < 4; ++bb) {
          float4 a[6];
#pragma unroll
          for (int c4 = 0; c4 < 6; ++c4)
            a[c4] = *(const float4*)(Bf + bb * 1536 + c4 * 256 + lane * 4);
#pragma unroll
          for (int g = 0; g < 4; ++g) {
            float s = acc[g][bb];
#pragma unroll
            for (int c4 = 0; c4 < 6; ++c4) {
              s += w0[g * 24 + c4 * 4 + 0] * a[c4].x;
              s += w0[g * 24 + c4 * 4 + 1] * a[c4].y;
              s += w0[g * 24 + c4 * 4 + 2] * a[c4].z;
              s += w0[g * 24 + c4 * 4 + 3] * a[c4].w;
            }
            acc[g][bb] = s;
          }
        }
#pragma unroll
        for (int bb = 0; bb < 4; ++bb) {
          int b = cch * 4 + bb;
          float s0 = wave_red_sum(acc[0][bb]);
          float s1 = wave_red_sum(acc[1][bb]);
          float s2 = wave_red_sum(acc[2][bb]);
          float s3 = wave_red_sum(acc[3][bb]);
          if (lane == b) { rg0 = s0; rg1 = s1; rg2 = s2; rg3 = s3; }
        }
        if (cch < 7) {   // write prefetched row into the other buffer
#pragma unroll
          for (int i = 0; i < 6; ++i) {
            int n = i * 64 + lane;
            int l = n / 6, c4 = n % 6;
            *(float4*)(lds + ((cch + 1) & 1) * 6144 + wv * 1536 + c4 * 256 + l * 4) = pf[i];
          }
        }
        __syncthreads();
      }

      // cell + zoneout, lane b < 32 handles (b, h)
      if (lane < NB) {
        const int b = lane;
        float i_ = sigmoidf_(rg0 + bia0[0]);
        float f_ = sigmoidf_(rg1 + bia0[1]);
        float g_ = tanhf(rg2 + bia0[2]);
        float o_ = sigmoidf_(rg3 + bia0[3]);
        size_t idx = (size_t)b * HID + h;
        float co = c0r[idx], ho = h0r[idx];
        float cn = f_ * co + i_ * g_;
        float hn = o_ * tanhf(cn);
        size_t uidx = (((size_t)t * 2 + 0) * NB + b) * HID + h;
        float hx = (u_h[uidx] < KEEPF) ? hn : ho;
        float cx = (u_c[uidx] < KEEPF) ? cn : co;
        h0w[idx] = hx; c0w[idx] = cx; o0w[idx] = hn;
        if (t == TSTEPS - 1) {
          out[(size_t)TSTEPS * STRIDE + idx] = hx;               // h_n[0]
          out[(size_t)TSTEPS * STRIDE + 2 * STRIDE + idx] = cx;  // c_n[0]
        }
      }
    }

    grid_sync(cnt, gen);   // o0w complete & visible; one sync per step

    // ================= Layer 1 =================
    {
      {
        const int b = wv;
        const float* orow = o0w + b * HID;
        const float* hrow = h1r + b * HID;
#pragma unroll
        for (int i = 0; i < 8; ++i) {
          int n = i * 64 + lane;                        // 0..511
          const float* src = (n < 256) ? (orow + 4 * n) : (hrow + 4 * n - HID);
          float4 v = *(const float4*)src;
          int l = n >> 3, c4 = n & 7;
          *(float4*)(lds + wv * 2048 + c4 * 256 + l * 4) = v;
        }
      }
      __syncthreads();

      for (int cch = 0; cch < 8; ++cch) {
        float4 pf[8];
        if (cch < 7) {
          const int b = (cch + 1) * 4 + wv;
          const float* orow = o0w + b * HID;
          const float* hrow = h1r + b * HID;
#pragma unroll
          for (int i = 0; i < 8; ++i) {
            int n = i * 64 + lane;
            const float* src = (n < 256) ? (orow + 4 * n) : (hrow + 4 * n - HID);
            pf[i] = *(const float4*)src;
          }
        }
        const float* Bf = lds + (cch & 1) * 8192;
        float acc[4][4];
#pragma unroll
        for (int g = 0; g < 4; ++g)
#pragma unroll
          for (int bb = 0; bb < 4; ++bb) acc[g][bb] = 0.f;

#pragma unroll
        for (int bb = 0; bb < 4; ++bb) {
          float4 a[8];
#pragma unroll
          for (int c4 = 0; c4 < 8; ++c4)
            a[c4] = *(const float4*)(Bf + bb * 2048 + c4 * 256 + lane * 4);
#pragma unroll
          for (int g = 0; g < 4; ++g) {
            float s = acc[g][bb];
#pragma unroll
            for (int c4 = 0; c4 < 8; ++c4) {
              s += w1[g * 32 + c4 * 4 + 0] * a[c4].x;
              s += w1[g * 32 + c4 * 4 + 1] * a[c4].y;
              s += w1[g * 32 + c4 * 4 + 2] * a[c4].z;
              s += w1[g * 32 + c4 * 4 + 3] * a[c4].w;
            }
            acc[g][bb] = s;
          }
        }
#pragma unroll
        for (int bb = 0; bb < 4; ++bb) {
          int b = cch * 4 + bb;
          float s0 = wave_red_sum(acc[0][bb]);
          float s1 = wave_red_sum(acc[1][bb]);
          float s2 = wave_red_sum(acc[2][bb]);
          float s3 = wave_red_sum(acc[3][bb]);
          if (lane == b) { rg0 = s0; rg1 = s1; rg2 = s2; rg3 = s3; }
        }
        if (cch < 7) {
#pragma unroll
          for (int i = 0; i < 8; ++i) {
            int n = i * 64 + lane;
            int l = n >> 3, c4 = n & 7;
            *(float4*)(lds + ((cch + 1) & 1) * 8192 + wv * 2048 + c4 * 256 + l * 4) = pf[i];
          }
        }
        __syncthreads();
      }

      if (lane < NB) {
        const int b = lane;
        float i_ = sigmoidf_(rg0 + bia1[0]);
        float f_ = sigmoidf_(rg1 + bia1[1]);
        float g_ = tanhf(rg2 + bia1[2]);
        float o_ = sigmoidf_(rg3 + bia1[3]);
        size_t idx = (size_t)b * HID + h;
        float co = c1r[idx], ho = h1r[idx];
        float cn = f_ * co + i_ * g_;
        float hn = o_ * tanhf(cn);
        size_t uidx = (((size_t)t * 2 + 1) * NB + b) * HID + h;
        float hx = (u_h[uidx] < KEEPF) ? hn : ho;
        float cx = (u_c[uidx] < KEEPF) ? cn : co;
        h1w[idx] = hx; c1w[idx] = cx;
        out[(size_t)t * STRIDE + idx] = hn;            // outputs[t] (pre-zoneout)
        if (t == TSTEPS - 1) {
          out[(size_t)TSTEPS * STRIDE + STRIDE + idx] = hx;       // h_n[1]
          out[(size_t)TSTEPS * STRIDE + 3 * STRIDE + idx] = cx;   // c_n[1]
        }
      }
    }
    // no grid sync here: L1(t) / L0(t+1) overlap is race-free via parity buffers
  }
}

// ---------------- host launch ----------------
extern "C" void kernel_launch(void* const* d_in, const int* in_sizes, int n_in,
                              void* d_out, int out_size, void* d_ws, size_t ws_size,
                              hipStream_t stream) {
  const float* x    = (const float*)d_in[0];
  const float* Wih0 = (const float*)d_in[1];
  const float* Whh0 = (const float*)d_in[2];
  const float* bih0 = (const float*)d_in[3];
  const float* bhh0 = (const float*)d_in[4];
  const float* Wih1 = (const float*)d_in[5];
  const float* Whh1 = (const float*)d_in[6];
  const float* bih1 = (const float*)d_in[7];
  const float* bhh1 = (const float*)d_in[8];
  const float* u_h  = (const float*)d_in[9];
  const float* u_c  = (const float*)d_in[10];
  float* out = (float*)d_out;
  float* ws  = (float*)d_ws;

  // zero barrier words + state buffers (ws is re-poisoned before every launch)
  hipLaunchKernelGGL(zo_init, dim3(1025), dim3(256), 0, stream, ws);
  // persistent cooperative kernel: 256 blocks (1/CU), 64 KiB dynamic LDS
  hipLaunchKernelGGL(zo_lstm, dim3(256), dim3(256), 65536, stream,
                     x, Wih0, Whh0, bih0, bhh0, Wih1, Whh1, bih1, bhh1,
                     u_h, u_c, out, ws);
}

// Round 9
// 30835.367 us; speedup vs baseline: 2.4945x; 2.4945x over previous
//
#include <hip/hip_runtime.h>
#include <cstdint>
#include <cstddef>

// Problem constants (T,B,D,H,L = 512,32,512,1024,2)
#define TSTEPS 512
#define NB     32
#define DIN    512
#define HID    1024
#define STRIDE 32768          // NB*HID floats
#define BAR_WORDS 256         // ws floats reserved for barrier words
#define KEEPF 0.9f            // 1 - p_zoneout

// ---------------- device helpers ----------------
template<int CTRL>
__device__ __forceinline__ float dpp_mov(float x) {
  return __int_as_float(__builtin_amdgcn_update_dpp(
      0, __float_as_int(x), CTRL, 0xf, 0xf, true));
}

// Full wave64 sum, DPP-only (VALU pipe), result broadcast via readlane.
__device__ __forceinline__ float wave_red_sum(float x) {
  x += dpp_mov<0x111>(x);   // row_shr:1
  x += dpp_mov<0x112>(x);   // row_shr:2
  x += dpp_mov<0x114>(x);   // row_shr:4
  x += dpp_mov<0x118>(x);   // row_shr:8
  x += dpp_mov<0x142>(x);   // row_bcast:15
  x += dpp_mov<0x143>(x);   // row_bcast:31
  return __int_as_float(__builtin_amdgcn_readlane(__float_as_int(x), 63));
}

__device__ __forceinline__ float sigmoidf_(float v) {
  return 1.0f / (1.0f + __expf(-v));
}

// async global->LDS, 16B per lane. dst must be wave-uniform; HW adds lane*16.
__device__ __forceinline__ void stage16(const float* src, float* dst) {
  __builtin_amdgcn_global_load_lds(
      (const __attribute__((address_space(1))) unsigned int*)src,
      (__attribute__((address_space(3))) unsigned int*)dst, 16, 0, 0);
}

// Hierarchical device-scope grid barrier: 32 blocks -> per-XCD counter,
// 8 XCD masters -> global counter -> gen bump. Fences once per block.
__device__ __forceinline__ void grid_sync(unsigned* bar, int myx) {
  __syncthreads();   // implies vmcnt(0): all this block's stores at least in L2
  if (threadIdx.x == 0) {
    __threadfence();  // release: push dirty L2 so other XCDs can see
    unsigned g = __hip_atomic_load(bar + 144, __ATOMIC_RELAXED, __HIP_MEMORY_SCOPE_AGENT);
    unsigned p = __hip_atomic_fetch_add(bar + myx * 16, 1u, __ATOMIC_ACQ_REL, __HIP_MEMORY_SCOPE_AGENT);
    if (p == 31u) {
      __hip_atomic_store(bar + myx * 16, 0u, __ATOMIC_RELAXED, __HIP_MEMORY_SCOPE_AGENT);
      unsigned q = __hip_atomic_fetch_add(bar + 128, 1u, __ATOMIC_ACQ_REL, __HIP_MEMORY_SCOPE_AGENT);
      if (q == 7u) {
        __hip_atomic_store(bar + 128, 0u, __ATOMIC_RELAXED, __HIP_MEMORY_SCOPE_AGENT);
        __hip_atomic_store(bar + 144, g + 1u, __ATOMIC_RELEASE, __HIP_MEMORY_SCOPE_AGENT);
      }
    }
    while (__hip_atomic_load(bar + 144, __ATOMIC_RELAXED, __HIP_MEMORY_SCOPE_AGENT) == g) {
      __builtin_amdgcn_s_sleep(8);
    }
    __threadfence();  // acquire: invalidate stale L1/L2
  }
  __syncthreads();
}

// Zero barrier words + h/c state (both parities) + o0.
__global__ void zo_init(float* ws) {
  size_t i = (size_t)blockIdx.x * blockDim.x + threadIdx.x;
  if (i < (size_t)BAR_WORDS + 10u * STRIDE) ws[i] = 0.0f;
}

// Persistent kernel: 256 blocks x 256 threads, 1 block/CU.
// wave owns h = (blk%8)*128 + (blk/8)*4 + wv  (XCD-local 64B lines).
// lane owns interleaved K-slices k = 4*lane + 256*i (contiguous LDS reads).
__global__ __launch_bounds__(256, 1)
void zo_lstm(const float* __restrict__ x,
             const float* __restrict__ Wih0, const float* __restrict__ Whh0,
             const float* __restrict__ bih0, const float* __restrict__ bhh0,
             const float* __restrict__ Wih1, const float* __restrict__ Whh1,
             const float* __restrict__ bih1, const float* __restrict__ bhh1,
             const float* __restrict__ u_h,  const float* __restrict__ u_c,
             float* __restrict__ out, float* __restrict__ ws)
{
  extern __shared__ float lds[];        // 16384 floats = 64 KiB
  const int tid  = threadIdx.x;
  const int lane = tid & 63;
  const int wv   = tid >> 6;            // wave in block, 0..3
  const int myx  = blockIdx.x & 7;      // assumed XCD id (perf-only)
  const int h    = myx * 128 + (blockIdx.x >> 3) * 4 + wv;   // 0..1023

  unsigned* bar = (unsigned*)ws;
  float* st  = ws + BAR_WORDS;
  float* h0s = st;                 // [2][NB][HID]
  float* c0s = st + 2 * STRIDE;
  float* h1s = st + 4 * STRIDE;
  float* c1s = st + 6 * STRIDE;
  float* o0s = st + 8 * STRIDE;    // [2][NB][HID] (pre-zoneout h0 -> L1 input)

  // ---- persistent weights in registers: interleaved slices ----
  // w0[(g*6+i)*4+j] = W0row(g*H+h)[4*lane + 256*i + j]   (i<2: Wih0, else Whh0)
  // w1[(g*8+i)*4+j] = W1row(g*H+h)[4*lane + 256*i + j]   (i<4: Wih1, else Whh1)
  float w0[96], w1[128], bia0[4], bia1[4];
#pragma unroll
  for (int g = 0; g < 4; ++g) {
    const int j = g * HID + h;
    const float* wi0 = Wih0 + (size_t)j * DIN;
    const float* wh0 = Whh0 + (size_t)j * HID;
#pragma unroll
    for (int i = 0; i < 6; ++i) {
      int k = 4 * lane + 256 * i;
      float4 v = (i < 2) ? *(const float4*)(wi0 + k)
                         : *(const float4*)(wh0 + (k - DIN));
      w0[(g * 6 + i) * 4 + 0] = v.x;  w0[(g * 6 + i) * 4 + 1] = v.y;
      w0[(g * 6 + i) * 4 + 2] = v.z;  w0[(g * 6 + i) * 4 + 3] = v.w;
    }
    const float* wi1 = Wih1 + (size_t)j * HID;
    const float* wh1 = Whh1 + (size_t)j * HID;
#pragma unroll
    for (int i = 0; i < 8; ++i) {
      int k = 4 * lane + 256 * i;
      float4 v = (i < 4) ? *(const float4*)(wi1 + k)
                         : *(const float4*)(wh1 + (k - HID));
      w1[(g * 8 + i) * 4 + 0] = v.x;  w1[(g * 8 + i) * 4 + 1] = v.y;
      w1[(g * 8 + i) * 4 + 2] = v.z;  w1[(g * 8 + i) * 4 + 3] = v.w;
    }
    bia0[g] = bih0[j] + bhh0[j];
    bia1[g] = bih1[j] + bhh1[j];
  }

  for (int t = 0; t < TSTEPS; ++t) {
    const int rp = t & 1, wp = rp ^ 1;
    const float* h0r = h0s + rp * STRIDE;  float* h0w = h0s + wp * STRIDE;
    const float* c0r = c0s + rp * STRIDE;  float* c0w = c0s + wp * STRIDE;
    const float* h1r = h1s + rp * STRIDE;  float* h1w = h1s + wp * STRIDE;
    const float* c1r = c1s + rp * STRIDE;  float* c1w = c1s + wp * STRIDE;
    float* o0w = o0s + wp * STRIDE;
    const float* xt = x + (size_t)t * NB * DIN;

    // ---- early prefetch of cell operands (all same-thread or pure input) ----
    const size_t idx = (size_t)lane * HID + h;   // valid use only when lane<NB
    float uh0 = 0.f, uc0 = 0.f, uh1 = 0.f, uc1 = 0.f;
    float hp0 = 0.f, cp0 = 0.f, hp1 = 0.f, cp1 = 0.f;
    if (lane < NB) {
      size_t ub0 = (((size_t)t * 2 + 0) * NB + lane) * HID + h;
      size_t ub1 = (((size_t)t * 2 + 1) * NB + lane) * HID + h;
      uh0 = u_h[ub0]; uc0 = u_c[ub0]; uh1 = u_h[ub1]; uc1 = u_c[ub1];
      hp0 = h0r[idx]; cp0 = c0r[idx]; hp1 = h1r[idx]; cp1 = c1r[idx];
    }

    float rg0 = 0.f, rg1 = 0.f, rg2 = 0.f, rg3 = 0.f;

    // ================= Layer 0 : rows = [x_t | h0] (1536) =================
    {
      {  // stage chunk 0 -> buf 0 (wave wv stages batch wv, 6x1KB)
        const float* xrow = xt + wv * DIN;
        const float* hrow = h0r + (size_t)wv * HID;
        float* dst = lds + wv * 1536;
#pragma unroll
        for (int i = 0; i < 6; ++i) {
          const float* src = (i < 2) ? (xrow + 4 * (i * 64 + lane))
                                     : (hrow + 4 * (i * 64 + lane) - DIN);
          stage16(src, dst + i * 256);
        }
      }
      __syncthreads();

      for (int cch = 0; cch < 8; ++cch) {
        if (cch < 7) {   // async prefetch next chunk into other buffer
          const int b = (cch + 1) * 4 + wv;
          const float* xrow = xt + b * DIN;
          const float* hrow = h0r + (size_t)b * HID;
          float* dst = lds + ((cch + 1) & 1) * 6144 + wv * 1536;
#pragma unroll
          for (int i = 0; i < 6; ++i) {
            const float* src = (i < 2) ? (xrow + 4 * (i * 64 + lane))
                                       : (hrow + 4 * (i * 64 + lane) - DIN);
            stage16(src, dst + i * 256);
          }
        }
        const float* Bf = lds + (cch & 1) * 6144;
        float acc[4][4];
#pragma unroll
        for (int g = 0; g < 4; ++g)
#pragma unroll
          for (int bb = 0; bb < 4; ++bb) acc[g][bb] = 0.f;

#pragma unroll
        for (int bb = 0; bb < 4; ++bb) {
          const float* rowp = Bf + bb * 1536 + 4 * lane;   // contiguous b128 reads
          float4 a[6];
#pragma unroll
          for (int i = 0; i < 6; ++i) a[i] = *(const float4*)(rowp + 256 * i);
#pragma unroll
          for (int g = 0; g < 4; ++g) {
            float s = acc[g][bb];
#pragma unroll
            for (int i = 0; i < 6; ++i) {
              s += w0[(g * 6 + i) * 4 + 0] * a[i].x;
              s += w0[(g * 6 + i) * 4 + 1] * a[i].y;
              s += w0[(g * 6 + i) * 4 + 2] * a[i].z;
              s += w0[(g * 6 + i) * 4 + 3] * a[i].w;
            }
            acc[g][bb] = s;
          }
        }
#pragma unroll
        for (int bb = 0; bb < 4; ++bb) {
          float s0 = wave_red_sum(acc[0][bb]);
          float s1 = wave_red_sum(acc[1][bb]);
          float s2 = wave_red_sum(acc[2][bb]);
          float s3 = wave_red_sum(acc[3][bb]);
          if (lane == cch * 4 + bb) { rg0 = s0; rg1 = s1; rg2 = s2; rg3 = s3; }
        }
        __syncthreads();
      }

      if (lane < NB) {   // cell + zoneout for (b=lane, h)
        float i_ = sigmoidf_(rg0 + bia0[0]);
        float f_ = sigmoidf_(rg1 + bia0[1]);
        float g_ = tanhf(rg2 + bia0[2]);
        float o_ = sigmoidf_(rg3 + bia0[3]);
        float cn = f_ * cp0 + i_ * g_;
        float hn = o_ * tanhf(cn);
        float hx = (uh0 < KEEPF) ? hn : hp0;
        float cx = (uc0 < KEEPF) ? cn : cp0;
        h0w[idx] = hx; c0w[idx] = cx; o0w[idx] = hn;
        if (t == TSTEPS - 1) {
          out[(size_t)TSTEPS * STRIDE + idx] = hx;               // h_n[0]
          out[(size_t)TSTEPS * STRIDE + 2 * STRIDE + idx] = cx;  // c_n[0]
        }
      }
    }

    grid_sync(bar, myx);   // one grid barrier per step

    // ================= Layer 1 : rows = [o0 | h1] (2048) =================
    {
      {
        const float* orow = o0w + (size_t)wv * HID;
        const float* hrow = h1r + (size_t)wv * HID;
        float* dst = lds + wv * 2048;
#pragma unroll
        for (int i = 0; i < 8; ++i) {
          const float* src = (i < 4) ? (orow + 4 * (i * 64 + lane))
                                     : (hrow + 4 * (i * 64 + lane) - HID);
          stage16(src, dst + i * 256);
        }
      }
      __syncthreads();

      for (int cch = 0; cch < 8; ++cch) {
        if (cch < 7) {
          const int b = (cch + 1) * 4 + wv;
          const float* orow = o0w + (size_t)b * HID;
          const float* hrow = h1r + (size_t)b * HID;
          float* dst = lds + ((cch + 1) & 1) * 8192 + wv * 2048;
#pragma unroll
          for (int i = 0; i < 8; ++i) {
            const float* src = (i < 4) ? (orow + 4 * (i * 64 + lane))
                                       : (hrow + 4 * (i * 64 + lane) - HID);
            stage16(src, dst + i * 256);
          }
        }
        const float* Bf = lds + (cch & 1) * 8192;
        float acc[4][4];
#pragma unroll
        for (int g = 0; g < 4; ++g)
#pragma unroll
          for (int bb = 0; bb < 4; ++bb) acc[g][bb] = 0.f;

#pragma unroll
        for (int bb = 0; bb < 4; ++bb) {
          const float* rowp = Bf + bb * 2048 + 4 * lane;
          float4 a[8];
#pragma unroll
          for (int i = 0; i < 8; ++i) a[i] = *(const float4*)(rowp + 256 * i);
#pragma unroll
          for (int g = 0; g < 4; ++g) {
            float s = acc[g][bb];
#pragma unroll
            for (int i = 0; i < 8; ++i) {
              s += w1[(g * 8 + i) * 4 + 0] * a[i].x;
              s += w1[(g * 8 + i) * 4 + 1] * a[i].y;
              s += w1[(g * 8 + i) * 4 + 2] * a[i].z;
              s += w1[(g * 8 + i) * 4 + 3] * a[i].w;
            }
            acc[g][bb] = s;
          }
        }
#pragma unroll
        for (int bb = 0; bb < 4; ++bb) {
          float s0 = wave_red_sum(acc[0][bb]);
          float s1 = wave_red_sum(acc[1][bb]);
          float s2 = wave_red_sum(acc[2][bb]);
          float s3 = wave_red_sum(acc[3][bb]);
          if (lane == cch * 4 + bb) { rg0 = s0; rg1 = s1; rg2 = s2; rg3 = s3; }
        }
        __syncthreads();
      }

      if (lane < NB) {
        float i_ = sigmoidf_(rg0 + bia1[0]);
        float f_ = sigmoidf_(rg1 + bia1[1]);
        float g_ = tanhf(rg2 + bia1[2]);
        float o_ = sigmoidf_(rg3 + bia1[3]);
        float cn = f_ * cp1 + i_ * g_;
        float hn = o_ * tanhf(cn);
        float hx = (uh1 < KEEPF) ? hn : hp1;
        float cx = (uc1 < KEEPF) ? cn : cp1;
        h1w[idx] = hx; c1w[idx] = cx;
        out[(size_t)t * STRIDE + idx] = hn;            // outputs[t] (pre-zoneout)
        if (t == TSTEPS - 1) {
          out[(size_t)TSTEPS * STRIDE + STRIDE + idx] = hx;       // h_n[1]
          out[(size_t)TSTEPS * STRIDE + 3 * STRIDE + idx] = cx;   // c_n[1]
        }
      }
    }
    // no grid sync here: L1(t) / L0(t+1) overlap is race-free via parity buffers
  }
}

// ---------------- host launch ----------------
extern "C" void kernel_launch(void* const* d_in, const int* in_sizes, int n_in,
                              void* d_out, int out_size, void* d_ws, size_t ws_size,
                              hipStream_t stream) {
  const float* x    = (const float*)d_in[0];
  const float* Wih0 = (const float*)d_in[1];
  const float* Whh0 = (const float*)d_in[2];
  const float* bih0 = (const float*)d_in[3];
  const float* bhh0 = (const float*)d_in[4];
  const float* Wih1 = (const float*)d_in[5];
  const float* Whh1 = (const float*)d_in[6];
  const float* bih1 = (const float*)d_in[7];
  const float* bhh1 = (const float*)d_in[8];
  const float* u_h  = (const float*)d_in[9];
  const float* u_c  = (const float*)d_in[10];
  float* out = (float*)d_out;
  float* ws  = (float*)d_ws;

  // zero barrier words + state buffers (ws is re-poisoned before every launch)
  hipLaunchKernelGGL(zo_init, dim3(1281), dim3(256), 0, stream, ws);
  // persistent kernel: 256 blocks (1/CU), 64 KiB dynamic LDS
  hipLaunchKernelGGL(zo_lstm, dim3(256), dim3(256), 65536, stream,
                     x, Wih0, Whh0, bih0, bhh0, Wih1, Whh1, bih1, bhh1,
                     u_h, u_c, out, ws);
}